// Round 3
// baseline (293.168 us; speedup 1.0000x reference)
//
#include <hip/hip_runtime.h>
#include <hip/hip_bf16.h>

typedef unsigned short u16;
typedef unsigned int   uint;
typedef __attribute__((ext_vector_type(8))) short bf16x8;
typedef __attribute__((ext_vector_type(4))) float f32x4;

constexpr int NELEM = 100;
constexpr int EMBED = 256;
constexpr int HID   = 512;
constexpr int KX    = 306;     // EMBED + 50
constexpr int G     = 50;
constexpr int M     = 64;      // edges (or pair-rows) per block
constexpr int THREADS = 512;   // 8 waves

// frag-ready weight buffers in d_ws (bf16):
//  Wb : [32 nt][10 ks][64 lane][8]  (k==306 row carries b_in; >306 zero)
//  Gb : [32 nt][ 2 ks][64 lane][8]  (g>=50 zero)
//  Ob : [16 slice][64 lane][8]      permuted W_out
//  hpre: [NPAIR][512] f32 (mode 4/2) or bf16 (mode 3/1) = emb_table @ W_emb.T
//  sorted modes add: perm[E] i32, pairids[E] u16, spair[E] u16, bins[NPAIR] i32
constexpr int WB_ELEMS = 32 * 10 * 64 * 8;   // 163840
constexpr int GB_ELEMS = 32 * 2 * 64 * 8;    // 32768
constexpr int OB_ELEMS = 16 * 64 * 8;        // 8192
constexpr int WEIGHT_ELEMS = WB_ELEMS + GB_ELEMS + OB_ELEMS;   // 204800
constexpr int NPREP = WEIGHT_ELEMS / THREADS;                  // 400 (exact)

__device__ __forceinline__ u16 f2bf(float x) {
    uint u = __float_as_uint(x);
    u = (u + 0x7fffu + ((u >> 16) & 1u)) >> 16;
    return (u16)u;
}
__device__ __forceinline__ uint pk2(float a, float b) {
    __hip_bfloat162 h = __float22bfloat162_rn(make_float2(a, b));
    return *reinterpret_cast<uint*>(&h);
}
__device__ __forceinline__ float bflo(uint u) { return __uint_as_float(u << 16); }
__device__ __forceinline__ float bfhi(uint u) { return __uint_as_float(u & 0xffff0000u); }
__device__ __forceinline__ float silu(float p) {
    return p * __builtin_amdgcn_rcpf(1.f + __expf(-p));
}
__device__ __forceinline__ f32x4 mfma16(bf16x8 a, bf16x8 b, f32x4 c) {
    return __builtin_amdgcn_mfma_f32_16x16x32_bf16(a, b, c, 0, 0, 0);
}

// ---- K2: weight frags (blocks < NPREP) + pair-id histogram (rest) ---------
__global__ __launch_bounds__(THREADS)
void prep_hist_kernel(const float* __restrict__ W_in,   // [512][306]
                      const float* __restrict__ gate_W, // [512][50]
                      const float* __restrict__ W_out,  // [8][512]
                      const float* __restrict__ b_in,   // [512]
                      const int* __restrict__ anum,
                      const int* __restrict__ edge_index,
                      const int* __restrict__ edge_to_src,
                      u16* __restrict__ Wb,
                      u16* __restrict__ Gb,
                      u16* __restrict__ Ob,
                      u16* __restrict__ pairids,
                      int* __restrict__ bins,
                      int E) {
    const int bid = blockIdx.x;
    const int t   = threadIdx.x;

    if (bid < NPREP) {                                  // ---- weight-frag part
        int idx = bid * THREADS + t;
        if (idx < WB_ELEMS) {
            int j = idx & 7, lane = (idx >> 3) & 63, kn = idx >> 9;
            int ks = kn % 10, nt = kn / 10;
            int h = nt * 16 + (lane & 15);
            int k = ks * 32 + (lane >> 4) * 8 + j;
            float v = (k < KX) ? W_in[h * KX + k] : ((k == KX) ? b_in[h] : 0.f);
            Wb[idx] = f2bf(v);
        } else if (idx < WB_ELEMS + GB_ELEMS) {
            int i2 = idx - WB_ELEMS;
            int j = i2 & 7, lane = (i2 >> 3) & 63, kn = i2 >> 9;
            int ks = kn & 1, nt = kn >> 1;
            int h = nt * 16 + (lane & 15);
            int g = ks * 32 + (lane >> 4) * 8 + j;
            Gb[i2] = f2bf((g < G) ? gate_W[h * G + g] : 0.f);
        } else {
            int i2 = idx - WB_ELEMS - GB_ELEMS;
            int j = i2 & 7, lane = (i2 >> 3) & 63, s = i2 >> 9;
            int m = lane & 15, q = lane >> 4;
            int hid = s * 32 + (j >> 2) * 16 + q * 4 + (j & 3);
            Ob[i2] = f2bf((m < 8) ? W_out[m * HID + hid] : 0.f);
        }
        return;
    }
    // ---- histogram part (only launched in sorted modes) --------------------
    int i = (bid - NPREP) * THREADS + t;
    if (i < E) {
        int src  = edge_to_src[i];
        int pair = anum[edge_index[src]] + NELEM * anum[edge_index[E + src]];
        pairids[i] = (u16)pair;
        atomicAdd(&bins[pair], 1);
    }
}

// ---- K3: exclusive scan of bins (in place: counts -> cursors) --------------
__global__ __launch_bounds__(THREADS)
void scan_kernel(int* __restrict__ bins, int npair) {
    __shared__ int lds[THREADS];
    const int t = threadIdx.x;
    const int chunk = (npair + THREADS - 1) / THREADS;
    const int lo = t * chunk;
    const int hi = min(lo + chunk, npair);
    int s = 0;
    for (int i = lo; i < hi; ++i) s += bins[i];
    lds[t] = s;
    __syncthreads();
    for (int off = 1; off < THREADS; off <<= 1) {
        int add = (t >= off) ? lds[t - off] : 0;
        __syncthreads();
        lds[t] += add;
        __syncthreads();
    }
    int excl = lds[t] - s;
    for (int i = lo; i < hi; ++i) {      // in place: each thread owns its chunk
        int c = bins[i];
        bins[i] = excl;
        excl += c;
    }
}

// ---- K4: scatter (blocks < nsc) + hpre GEMM from Wb frags (rest) -----------
__global__ __launch_bounds__(THREADS)
void scatter_hpre_kernel(const float* __restrict__ table,  // emb f32 [NPAIR][256]
                         const u16* __restrict__ Wb,
                         const u16* __restrict__ pairids,
                         int* __restrict__ bins,           // cursors after scan
                         int* __restrict__ perm,
                         u16* __restrict__ spair,
                         float* __restrict__ hpreF,
                         u16*   __restrict__ hpreH,
                         int E, int npair, int nsc, int f32h) {
    __shared__ __align__(16) u16 af[8 * 4 * 64 * 8];   // 32 KB A-tile (hpre part)
    const int bid = blockIdx.x;
    const int t   = threadIdx.x;

    if (bid < nsc) {                                    // ---- scatter part
        int i = bid * THREADS + t;
        if (i < E) {
            int p   = pairids[i];
            int pos = atomicAdd(&bins[p], 1);
            perm[pos]  = i;
            spair[pos] = (u16)p;
        }
        return;
    }

    // ---- hpre[p][h] = sum_{k<256} emb[p][k] * W_in[h][k] -------------------
    // Same MFMA sequence (ks 0..7, Wb frags) as the fused kernel, so the main
    // kernel's acc-init + ks 8..9 continuation is bit-identical accumulation.
    const int pb = bid - nsc;
    const int p0 = pb * M;
    const int wave = t >> 6, lane = t & 63;
    const int col = lane & 15, quad = lane >> 4;

    #pragma unroll
    for (int mt = 0; mt < 4; ++mt) {
        int p = p0 + mt * 16 + col;
        uint4 w = {0u, 0u, 0u, 0u};
        if (p < npair) {
            const float* s = table + (size_t)p * EMBED + wave * 32 + quad * 8;
            float4 v0 = ((const float4*)s)[0], v1 = ((const float4*)s)[1];
            w.x = pk2(v0.x, v0.y); w.y = pk2(v0.z, v0.w);
            w.z = pk2(v1.x, v1.y); w.w = pk2(v1.z, v1.w);
        }
        *(uint4*)&af[((wave * 4 + mt) * 64 + lane) * 8] = w;
    }
    __syncthreads();

    const f32x4 z4 = {0.f, 0.f, 0.f, 0.f};
    #pragma unroll
    for (int nh = 0; nh < 2; ++nh) {
        f32x4 acc[2][4];
        #pragma unroll
        for (int ntl = 0; ntl < 2; ++ntl)
            #pragma unroll
            for (int mt = 0; mt < 4; ++mt) acc[ntl][mt] = z4;
        #pragma unroll 2
        for (int ks = 0; ks < 8; ++ks) {
            bf16x8 a[4];
            #pragma unroll
            for (int mt = 0; mt < 4; ++mt)
                a[mt] = *(const bf16x8*)&af[((ks * 4 + mt) * 64 + lane) * 8];
            #pragma unroll
            for (int ntl = 0; ntl < 2; ++ntl) {
                int ntg = wave * 4 + nh * 2 + ntl;
                bf16x8 wf = *(const bf16x8*)&Wb[((ntg * 10 + ks) * 64 + lane) * 8];
                #pragma unroll
                for (int mt = 0; mt < 4; ++mt)
                    acc[ntl][mt] = mfma16(wf, a[mt], acc[ntl][mt]);
            }
        }
        #pragma unroll
        for (int ntl = 0; ntl < 2; ++ntl)
            #pragma unroll
            for (int mt = 0; mt < 4; ++mt) {
                int p = p0 + mt * 16 + col;
                if (p < npair) {
                    int hb = (wave * 4 + nh * 2 + ntl) * 16 + quad * 4;
                    if (f32h) {
                        *(f32x4*)(hpreF + (size_t)p * HID + hb) = acc[ntl][mt];
                    } else {
                        uint2 o;
                        o.x = pk2(acc[ntl][mt][0], acc[ntl][mt][1]);
                        o.y = pk2(acc[ntl][mt][2], acc[ntl][mt][3]);
                        *(uint2*)(hpreH + (size_t)p * HID + hb) = o;
                    }
                }
            }
    }
}

// ---- sorted main kernel: block = 64 consecutive sorted edges ---------------
// ~2 distinct hpre rows per block -> gathers are L1/L2 hits.
template <bool F32H>
__global__ __launch_bounds__(THREADS, 4)
void pair_embed_srt(const int* __restrict__ perm,
                    const u16* __restrict__ spair,
                    const float* __restrict__ dist,
                    const float* __restrict__ hpreF,
                    const u16*   __restrict__ hpreH,
                    const float* __restrict__ b_out,
                    const u16* __restrict__ Wb,
                    const u16* __restrict__ Gb,
                    const u16* __restrict__ Ob,
                    float* __restrict__ out,
                    int E) {
    // smem: afrag (rbf A-tile, first 8 KB) unions with redf (full 32 KB)
    __shared__ __align__(16) u16 smem[16384];
    __shared__ int   rowbase[M];
    __shared__ float dste[M];
    __shared__ int   oidx[M];
    u16*   afrag = smem;
    float* redf  = (float*)smem;     // [8 wave][4 mt][64 lane][4]

    const int t  = threadIdx.x;
    const int e0 = blockIdx.x * M;
    const int wave = t >> 6, lane = t & 63;
    const int col = lane & 15, quad = lane >> 4;

    if (t < M) {
        int slot = e0 + t;
        int pair = 0, orig = 0; float d = 0.f;
        if (slot < E) {
            orig = perm[slot];
            pair = spair[slot];
            d    = dist[orig];
        }
        rowbase[t] = pair * HID;
        dste[t]    = d;
        oidx[t]    = orig;
    }
    __syncthreads();

    int rbm[4];
    #pragma unroll
    for (int mt = 0; mt < 4; ++mt) rbm[mt] = rowbase[mt * 16 + col];

    f32x4 hp[2][4];
    uint2 hph[2][4];
    #pragma unroll
    for (int mt = 0; mt < 4; ++mt) {
        int base = rbm[mt] + (wave * 4) * 16 + quad * 4;
        if (F32H) {
            const float* p = hpreF + base;
            hp[0][mt] = *(const f32x4*)p;
            hp[1][mt] = *(const f32x4*)(p + 16);
        } else {
            const u16* p = hpreH + base;
            hph[0][mt] = *(const uint2*)p;
            hph[1][mt] = *(const uint2*)(p + 16);
        }
    }

    // ---- stage rbf A-tile: wave w -> (ks = w&1, mt = w>>1) -----------------
    {
        const float sp    = 12.0f / 49.0f;
        const float coeff = -0.5f / (sp * sp);
        int ks = wave & 1, mtr = wave >> 1;
        float d  = dste[mtr * 16 + col];
        int   g0 = ks * 32 + quad * 8;
        float f[8];
        #pragma unroll
        for (int j = 0; j < 8; ++j) {
            int g = g0 + j;
            float dd = d - sp * (float)g;
            f[j] = (g < G) ? __expf(coeff * dd * dd) : ((g == G) ? 1.f : 0.f);
        }
        uint4 w;
        w.x = pk2(f[0], f[1]); w.y = pk2(f[2], f[3]);
        w.z = pk2(f[4], f[5]); w.w = pk2(f[6], f[7]);
        *(uint4*)&afrag[((ks * 4 + mtr) * 64 + lane) * 8] = w;
    }
    __syncthreads();

    const f32x4 z4 = {0.f, 0.f, 0.f, 0.f};
    f32x4 oacc[4] = {z4, z4, z4, z4};

    #pragma unroll
    for (int nh = 0; nh < 2; ++nh) {
        if (nh == 1) {
            #pragma unroll
            for (int mt = 0; mt < 4; ++mt) {
                int base = rbm[mt] + (wave * 4 + 2) * 16 + quad * 4;
                if (F32H) {
                    const float* p = hpreF + base;
                    hp[0][mt] = *(const f32x4*)p;
                    hp[1][mt] = *(const f32x4*)(p + 16);
                } else {
                    const u16* p = hpreH + base;
                    hph[0][mt] = *(const uint2*)p;
                    hph[1][mt] = *(const uint2*)(p + 16);
                }
            }
        }
        f32x4 acc[2][4], gacc[2][4];
        #pragma unroll
        for (int ntl = 0; ntl < 2; ++ntl)
            #pragma unroll
            for (int mt = 0; mt < 4; ++mt) {
                gacc[ntl][mt] = z4;
                if (F32H) {
                    acc[ntl][mt] = hp[ntl][mt];
                } else {
                    uint2 v = hph[ntl][mt];
                    f32x4 a = {bflo(v.x), bfhi(v.x), bflo(v.y), bfhi(v.y)};
                    acc[ntl][mt] = a;
                }
            }

        const u16* gb = &Gb[((wave * 4 + nh * 2) * 2 * 64 + lane) * 8];
        const u16* wb = &Wb[(((wave * 4 + nh * 2) * 10 + 8) * 64 + lane) * 8];
        #pragma unroll
        for (int ks = 0; ks < 2; ++ks) {
            bf16x8 a[4];
            #pragma unroll
            for (int mt = 0; mt < 4; ++mt)
                a[mt] = *(const bf16x8*)&afrag[((ks * 4 + mt) * 64 + lane) * 8];
            bf16x8 g0f = *(const bf16x8*)&gb[ks * 512];
            bf16x8 w0f = *(const bf16x8*)&wb[ks * 512];
            bf16x8 g1f = *(const bf16x8*)&gb[1024 + ks * 512];
            bf16x8 w1f = *(const bf16x8*)&wb[5120 + ks * 512];
            #pragma unroll
            for (int mt = 0; mt < 4; ++mt) gacc[0][mt] = mfma16(g0f, a[mt], gacc[0][mt]);
            #pragma unroll
            for (int mt = 0; mt < 4; ++mt) acc[0][mt]  = mfma16(w0f, a[mt], acc[0][mt]);
            #pragma unroll
            for (int mt = 0; mt < 4; ++mt) gacc[1][mt] = mfma16(g1f, a[mt], gacc[1][mt]);
            #pragma unroll
            for (int mt = 0; mt < 4; ++mt) acc[1][mt]  = mfma16(w1f, a[mt], acc[1][mt]);
        }

        bf16x8 obf = *(const bf16x8*)&Ob[(((wave << 1) | nh) * 64 + lane) * 8];
        #pragma unroll
        for (int mt = 0; mt < 4; ++mt) {
            uint4 hq;
            hq.x = pk2(silu(acc[0][mt][0]) * gacc[0][mt][0],
                       silu(acc[0][mt][1]) * gacc[0][mt][1]);
            hq.y = pk2(silu(acc[0][mt][2]) * gacc[0][mt][2],
                       silu(acc[0][mt][3]) * gacc[0][mt][3]);
            hq.z = pk2(silu(acc[1][mt][0]) * gacc[1][mt][0],
                       silu(acc[1][mt][1]) * gacc[1][mt][1]);
            hq.w = pk2(silu(acc[1][mt][2]) * gacc[1][mt][2],
                       silu(acc[1][mt][3]) * gacc[1][mt][3]);
            oacc[mt] = mfma16(obf, *(bf16x8*)&hq, oacc[mt]);
        }
    }
    __syncthreads();

    #pragma unroll
    for (int mt = 0; mt < 4; ++mt)
        *(f32x4*)&redf[((wave * 4 + mt) * 64 + lane) * 4] = oacc[mt];
    __syncthreads();

    {
        int head = t >> 6, el = t & 63;
        int mt = el >> 4, c = el & 15;
        int l  = (head >> 2) * 16 + c;
        int r  = head & 3;
        float s = 0.f;
        #pragma unroll
        for (int w = 0; w < 8; ++w)
            s += redf[((w * 4 + mt) * 64 + l) * 4 + r];
        int slot = e0 + el;
        if (slot < E) out[head * E + oidx[el]] = s + b_out[head];
    }
}

// ---- unsorted main (fallback, modes 2/1): gather hpre per edge -------------
template <bool F32H>
__global__ __launch_bounds__(THREADS, 4)
void pair_embed_pre(const int* __restrict__ anum,
                    const int* __restrict__ edge_index,
                    const int* __restrict__ edge_to_src,
                    const float* __restrict__ dist,
                    const float* __restrict__ hpreF,
                    const u16*   __restrict__ hpreH,
                    const float* __restrict__ b_out,
                    const u16* __restrict__ Wb,
                    const u16* __restrict__ Gb,
                    const u16* __restrict__ Ob,
                    float* __restrict__ out,
                    int E) {
    __shared__ __align__(16) u16 smem[16384];
    __shared__ int   rowbase[M];
    __shared__ float dste[M];
    u16*   afrag = smem;
    float* redf  = (float*)smem;

    const int t  = threadIdx.x;
    const int e0 = blockIdx.x * M;
    const int wave = t >> 6, lane = t & 63;
    const int col = lane & 15, quad = lane >> 4;

    if (t < M) {
        int eg = e0 + t;
        int pair = 0; float d = 0.f;
        if (eg < E) {
            int src = edge_to_src[eg];
            pair = anum[edge_index[src]] + NELEM * anum[edge_index[E + src]];
            d = dist[eg];
        }
        rowbase[t] = pair * HID;
        dste[t]    = d;
    }
    __syncthreads();

    int rbm[4];
    #pragma unroll
    for (int mt = 0; mt < 4; ++mt) rbm[mt] = rowbase[mt * 16 + col];

    f32x4 hp[2][4];
    uint2 hph[2][4];
    #pragma unroll
    for (int mt = 0; mt < 4; ++mt) {
        int base = rbm[mt] + (wave * 4) * 16 + quad * 4;
        if (F32H) {
            const float* p = hpreF + base;
            hp[0][mt] = *(const f32x4*)p;
            hp[1][mt] = *(const f32x4*)(p + 16);
        } else {
            const u16* p = hpreH + base;
            hph[0][mt] = *(const uint2*)p;
            hph[1][mt] = *(const uint2*)(p + 16);
        }
    }

    {
        const float sp    = 12.0f / 49.0f;
        const float coeff = -0.5f / (sp * sp);
        int ks = wave & 1, mtr = wave >> 1;
        float d  = dste[mtr * 16 + col];
        int   g0 = ks * 32 + quad * 8;
        float f[8];
        #pragma unroll
        for (int j = 0; j < 8; ++j) {
            int g = g0 + j;
            float dd = d - sp * (float)g;
            f[j] = (g < G) ? __expf(coeff * dd * dd) : ((g == G) ? 1.f : 0.f);
        }
        uint4 w;
        w.x = pk2(f[0], f[1]); w.y = pk2(f[2], f[3]);
        w.z = pk2(f[4], f[5]); w.w = pk2(f[6], f[7]);
        *(uint4*)&afrag[((ks * 4 + mtr) * 64 + lane) * 8] = w;
    }
    __syncthreads();

    const f32x4 z4 = {0.f, 0.f, 0.f, 0.f};
    f32x4 oacc[4] = {z4, z4, z4, z4};

    #pragma unroll
    for (int nh = 0; nh < 2; ++nh) {
        if (nh == 1) {
            #pragma unroll
            for (int mt = 0; mt < 4; ++mt) {
                int base = rbm[mt] + (wave * 4 + 2) * 16 + quad * 4;
                if (F32H) {
                    const float* p = hpreF + base;
                    hp[0][mt] = *(const f32x4*)p;
                    hp[1][mt] = *(const f32x4*)(p + 16);
                } else {
                    const u16* p = hpreH + base;
                    hph[0][mt] = *(const uint2*)p;
                    hph[1][mt] = *(const uint2*)(p + 16);
                }
            }
        }
        f32x4 acc[2][4], gacc[2][4];
        #pragma unroll
        for (int ntl = 0; ntl < 2; ++ntl)
            #pragma unroll
            for (int mt = 0; mt < 4; ++mt) {
                gacc[ntl][mt] = z4;
                if (F32H) {
                    acc[ntl][mt] = hp[ntl][mt];
                } else {
                    uint2 v = hph[ntl][mt];
                    f32x4 a = {bflo(v.x), bfhi(v.x), bflo(v.y), bfhi(v.y)};
                    acc[ntl][mt] = a;
                }
            }

        const u16* gb = &Gb[((wave * 4 + nh * 2) * 2 * 64 + lane) * 8];
        const u16* wb = &Wb[(((wave * 4 + nh * 2) * 10 + 8) * 64 + lane) * 8];
        #pragma unroll
        for (int ks = 0; ks < 2; ++ks) {
            bf16x8 a[4];
            #pragma unroll
            for (int mt = 0; mt < 4; ++mt)
                a[mt] = *(const bf16x8*)&afrag[((ks * 4 + mt) * 64 + lane) * 8];
            bf16x8 g0f = *(const bf16x8*)&gb[ks * 512];
            bf16x8 w0f = *(const bf16x8*)&wb[ks * 512];
            bf16x8 g1f = *(const bf16x8*)&gb[1024 + ks * 512];
            bf16x8 w1f = *(const bf16x8*)&wb[5120 + ks * 512];
            #pragma unroll
            for (int mt = 0; mt < 4; ++mt) gacc[0][mt] = mfma16(g0f, a[mt], gacc[0][mt]);
            #pragma unroll
            for (int mt = 0; mt < 4; ++mt) acc[0][mt]  = mfma16(w0f, a[mt], acc[0][mt]);
            #pragma unroll
            for (int mt = 0; mt < 4; ++mt) gacc[1][mt] = mfma16(g1f, a[mt], gacc[1][mt]);
            #pragma unroll
            for (int mt = 0; mt < 4; ++mt) acc[1][mt]  = mfma16(w1f, a[mt], acc[1][mt]);
        }

        bf16x8 obf = *(const bf16x8*)&Ob[(((wave << 1) | nh) * 64 + lane) * 8];
        #pragma unroll
        for (int mt = 0; mt < 4; ++mt) {
            uint4 hq;
            hq.x = pk2(silu(acc[0][mt][0]) * gacc[0][mt][0],
                       silu(acc[0][mt][1]) * gacc[0][mt][1]);
            hq.y = pk2(silu(acc[0][mt][2]) * gacc[0][mt][2],
                       silu(acc[0][mt][3]) * gacc[0][mt][3]);
            hq.z = pk2(silu(acc[1][mt][0]) * gacc[1][mt][0],
                       silu(acc[1][mt][1]) * gacc[1][mt][1]);
            hq.w = pk2(silu(acc[1][mt][2]) * gacc[1][mt][2],
                       silu(acc[1][mt][3]) * gacc[1][mt][3]);
            oacc[mt] = mfma16(obf, *(bf16x8*)&hq, oacc[mt]);
        }
    }
    __syncthreads();

    #pragma unroll
    for (int mt = 0; mt < 4; ++mt)
        *(f32x4*)&redf[((wave * 4 + mt) * 64 + lane) * 4] = oacc[mt];
    __syncthreads();

    {
        int head = t >> 6, el = t & 63;
        int mt = el >> 4, c = el & 15;
        int l  = (head >> 2) * 16 + c;
        int r  = head & 3;
        float s = 0.f;
        #pragma unroll
        for (int w = 0; w < 8; ++w)
            s += redf[((w * 4 + mt) * 64 + l) * 4 + r];
        int eg = e0 + el;
        if (eg < E) out[head * E + eg] = s + b_out[head];
    }
}

extern "C" void kernel_launch(void* const* d_in, const int* in_sizes, int n_in,
                              void* d_out, int out_size, void* d_ws, size_t ws_size,
                              hipStream_t stream) {
    const int*   anum        = (const int*)d_in[0];
    const int*   edge_index  = (const int*)d_in[1];
    const int*   edge_to_src = (const int*)d_in[2];
    const float* dist        = (const float*)d_in[3];
    const float* emb_table   = (const float*)d_in[4];
    const float* gate_W      = (const float*)d_in[5];
    const float* W_in        = (const float*)d_in[6];
    const float* b_in        = (const float*)d_in[7];
    const float* W_out       = (const float*)d_in[8];
    const float* b_out       = (const float*)d_in[9];
    const int E     = in_sizes[3];
    const int TBL   = in_sizes[4];            // NELEM^2 * EMBED elements
    const int NPAIR = TBL / EMBED;

    u16* Wb = (u16*)d_ws;
    u16* Gb = Wb + WB_ELEMS;
    u16* Ob = Gb + GB_ELEMS;
    const size_t WSW  = (size_t)WEIGHT_ELEMS * 2;       // 409600 B
    const size_t hb32 = (size_t)NPAIR * HID * 4;
    const size_t hb16 = (size_t)NPAIR * HID * 2;
    const size_t sortx = (size_t)E * 8 + (size_t)NPAIR * 4;

    // mode: 4 sorted+f32, 3 sorted+bf16, 2 unsorted+f32, 1 unsorted+bf16, 0 old-path-less (skip)
    int mode;
    if      (ws_size >= WSW + hb32 + sortx) mode = 4;
    else if (ws_size >= WSW + hb16 + sortx) mode = 3;
    else if (ws_size >= WSW + hb32)         mode = 2;
    else                                    mode = 1;   // hb16 minimal: 10.65 MB

    const size_t hb = (mode == 4 || mode == 2) ? hb32 : hb16;
    char*  hbase   = (char*)d_ws + WSW;
    float* hpreF   = (float*)hbase;
    u16*   hpreH   = (u16*)hbase;
    char*  q       = hbase + hb;
    int*   perm    = (int*)q;
    u16*   pairids = (u16*)(q + (size_t)E * 4);
    u16*   spair   = (u16*)(q + (size_t)E * 6);
    int*   bins    = (int*)(q + (size_t)E * 8);

    const int nhist   = (E + THREADS - 1) / THREADS;
    const int npb     = (NPAIR + M - 1) / M;
    const int nblocks = (E + M - 1) / M;
    const int f32h    = (mode == 4 || mode == 2) ? 1 : 0;

    if (mode >= 3) {
        hipMemsetAsync(bins, 0, (size_t)NPAIR * 4, stream);
        prep_hist_kernel<<<NPREP + nhist, THREADS, 0, stream>>>(
            W_in, gate_W, W_out, b_in, anum, edge_index, edge_to_src,
            Wb, Gb, Ob, pairids, bins, E);
        scan_kernel<<<1, THREADS, 0, stream>>>(bins, NPAIR);
        scatter_hpre_kernel<<<nhist + npb, THREADS, 0, stream>>>(
            emb_table, Wb, pairids, bins, perm, spair, hpreF, hpreH,
            E, NPAIR, nhist, f32h);
        if (mode == 4) {
            pair_embed_srt<true><<<nblocks, THREADS, 0, stream>>>(
                perm, spair, dist, hpreF, hpreH, b_out, Wb, Gb, Ob, (float*)d_out, E);
        } else {
            pair_embed_srt<false><<<nblocks, THREADS, 0, stream>>>(
                perm, spair, dist, hpreF, hpreH, b_out, Wb, Gb, Ob, (float*)d_out, E);
        }
    } else {
        prep_hist_kernel<<<NPREP, THREADS, 0, stream>>>(
            W_in, gate_W, W_out, b_in, anum, edge_index, edge_to_src,
            Wb, Gb, Ob, pairids, bins, E);
        scatter_hpre_kernel<<<npb, THREADS, 0, stream>>>(
            emb_table, Wb, pairids, bins, perm, spair, hpreF, hpreH,
            E, NPAIR, 0, f32h);
        if (mode == 2) {
            pair_embed_pre<true><<<nblocks, THREADS, 0, stream>>>(
                anum, edge_index, edge_to_src, dist, hpreF, hpreH,
                b_out, Wb, Gb, Ob, (float*)d_out, E);
        } else {
            pair_embed_pre<false><<<nblocks, THREADS, 0, stream>>>(
                anum, edge_index, edge_to_src, dist, hpreF, hpreH,
                b_out, Wb, Gb, Ob, (float*)d_out, E);
        }
    }
}